// Round 5
// baseline (123.547 us; speedup 1.0000x reference)
//
#include <hip/hip_runtime.h>
#include <hip/hip_bf16.h>

#define BB 16
#define NQ 64
#define NK 512
#define HD 256   // H = QS = KS = VD = 256

typedef __attribute__((ext_vector_type(8))) short short8;
typedef __attribute__((ext_vector_type(4))) float f32x4;

// fp32 -> bf16 round-to-nearest-even, bit-level
__device__ __forceinline__ ushort bf16_rne(float v) {
    unsigned u = __float_as_uint(v);
    return (ushort)((u + 0x7FFFu + ((u >> 16) & 1u)) >> 16);
}
__device__ __forceinline__ float bf16_to_f(ushort h) {
    return __uint_as_float(((unsigned)h) << 16);
}

// ---------------------------------------------------------------------------
// One-shot conversion (memory-bound, ~10 MB):
//   queries/keys fp32 -> hi/lo bf16 arrays (same [row][k] layout)
//   W_q/W_k fp32 [k][n] -> hi/lo bf16 TRANSPOSED [n][k] (B-frag friendly)
// ---------------------------------------------------------------------------
__global__ __launch_bounds__(256) void convert_split(
    const float* __restrict__ q, const float* __restrict__ k,
    const float* __restrict__ wq, const float* __restrict__ wk,
    ushort* __restrict__ qh, ushort* __restrict__ ql,
    ushort* __restrict__ kh, ushort* __restrict__ kl,
    ushort* __restrict__ wqh, ushort* __restrict__ wql,
    ushort* __restrict__ wkh, ushort* __restrict__ wkl)
{
    const int idx = blockIdx.x * 256 + threadIdx.x;
    if (blockIdx.x < 2304) {                     // A-part: (1024+8192)*256 elems
        int e = idx * 4;
        const float* src; ushort *dh, *dl; int off;
        if (e < 1024 * 256) { src = q; dh = qh; dl = ql; off = e; }
        else { src = k; dh = kh; dl = kl; off = e - 1024 * 256; }
        float4 v = *(const float4*)&src[off];
        float fv[4] = {v.x, v.y, v.z, v.w};
        ushort hh[4], ll[4];
        #pragma unroll
        for (int c = 0; c < 4; ++c) {
            hh[c] = bf16_rne(fv[c]);
            ll[c] = bf16_rne(fv[c] - bf16_to_f(hh[c]));
        }
        *(ushort4*)&dh[off] = make_ushort4(hh[0], hh[1], hh[2], hh[3]);
        *(ushort4*)&dl[off] = make_ushort4(ll[0], ll[1], ll[2], ll[3]);
    } else {                                     // W-part: 2 x 256x256, transpose
        int widx = idx - 2304 * 256;             // 0..32767
        const float* W; ushort *wh, *wl;
        if (widx < 16384) { W = wq; wh = wqh; wl = wql; }
        else { W = wk; wh = wkh; wl = wkl; widx -= 16384; }
        int kk = widx >> 6;                      // 0..255
        int n4 = (widx & 63) * 4;
        float4 v = *(const float4*)&W[kk * 256 + n4];
        float fv[4] = {v.x, v.y, v.z, v.w};
        #pragma unroll
        for (int c = 0; c < 4; ++c) {
            ushort hh = bf16_rne(fv[c]);
            wh[(n4 + c) * 256 + kk] = hh;
            wl[(n4 + c) * 256 + kk] = bf16_rne(fv[c] - bf16_to_f(hh));
        }
    }
}

// ---------------------------------------------------------------------------
// Lean split-bf16 MFMA GEMM:  C = A @ W  (3 products: AhWh + AlWh + AhWl),
// epilogue * scale.  Block tile 128x64, BK=64, 4 waves (each 32x64).
// LDS layout: unpadded rows of 8 x 16B chunks with XOR swizzle
//   LDS[row][c] = A[row][c ^ (row&7)]  -> frag reads spread banks.
// Frags (verified gfx950 16x16x32 bf16):
//   A[m=lane&15][k=quad*8+j], B(row of W^T)[n=lane&15][k=quad*8+j],
//   C/D col=lane&15, row=quad*4+reg.
// ---------------------------------------------------------------------------
__global__ __launch_bounds__(256, 2) void proj_mfma2(
    const ushort* __restrict__ qh, const ushort* __restrict__ ql,
    const ushort* __restrict__ kh, const ushort* __restrict__ kl,
    const ushort* __restrict__ wqh, const ushort* __restrict__ wql,
    const ushort* __restrict__ wkh, const ushort* __restrict__ wkl,
    float* __restrict__ qp, float* __restrict__ kp, float scale)
{
    __shared__ ushort AsH[128 * 64], AsL[128 * 64];
    __shared__ ushort BsH[64 * 64],  BsL[64 * 64];

    const ushort *Ah, *Al, *Bh, *Bl; float* C; int rows0;
    if (blockIdx.x < 8) { Ah = qh; Al = ql; Bh = wqh; Bl = wql; C = qp; rows0 = blockIdx.x * 128; }
    else                { Ah = kh; Al = kl; Bh = wkh; Bl = wkl; C = kp; rows0 = (blockIdx.x - 8) * 128; }
    const int cols0 = blockIdx.y * 64;

    const int t = threadIdx.x, lane = t & 63, wave = t >> 6;
    const int quad = lane >> 4, l15 = lane & 15;
    const int lr = lane >> 3;        // row-within-8 for staging
    const int cg = (lane & 7) ^ lr;  // swizzled global chunk (per-lane const)
    const int swz0 = quad ^ (l15 & 7);
    const int swz1 = (quad + 4) ^ (l15 & 7);

    f32x4 acc[2][4];
    #pragma unroll
    for (int i = 0; i < 2; ++i)
        #pragma unroll
        for (int j = 0; j < 4; ++j)
            acc[i][j] = (f32x4){0.f, 0.f, 0.f, 0.f};

    for (int k0 = 0; k0 < 256; k0 += 64) {
        // global -> regs (overlaps previous iteration's compute)
        short8 rAh[4], rAl[4], rBh[2], rBl[2];
        #pragma unroll
        for (int i = 0; i < 4; ++i) {
            int ii = wave * 4 + i;
            size_t g = (size_t)(rows0 + ii * 8 + lr) * 256 + k0 + cg * 8;
            rAh[i] = *(const short8*)&Ah[g];
            rAl[i] = *(const short8*)&Al[g];
        }
        #pragma unroll
        for (int j = 0; j < 2; ++j) {
            int jj = wave * 2 + j;
            size_t g = (size_t)(cols0 + jj * 8 + lr) * 256 + k0 + cg * 8;
            rBh[j] = *(const short8*)&Bh[g];
            rBl[j] = *(const short8*)&Bl[g];
        }
        __syncthreads();   // previous compute done before LDS overwrite

        // regs -> LDS (chunk index = ii*64 + lane; content = swizzled chunk)
        #pragma unroll
        for (int i = 0; i < 4; ++i) {
            int ci = (wave * 4 + i) * 64 + lane;
            *(short8*)&AsH[ci * 8] = rAh[i];
            *(short8*)&AsL[ci * 8] = rAl[i];
        }
        #pragma unroll
        for (int j = 0; j < 2; ++j) {
            int ci = (wave * 2 + j) * 64 + lane;
            *(short8*)&BsH[ci * 8] = rBh[j];
            *(short8*)&BsL[ci * 8] = rBl[j];
        }
        __syncthreads();

        #pragma unroll
        for (int ks = 0; ks < 2; ++ks) {
            const int s = ks ? swz1 : swz0;
            short8 aH[2], aL[2], bH[4], bL[4];
            #pragma unroll
            for (int ms = 0; ms < 2; ++ms) {
                int r = wave * 32 + ms * 16 + l15;
                aH[ms] = *(const short8*)&AsH[r * 64 + s * 8];
                aL[ms] = *(const short8*)&AsL[r * 64 + s * 8];
            }
            #pragma unroll
            for (int ns = 0; ns < 4; ++ns) {
                int n = ns * 16 + l15;
                bH[ns] = *(const short8*)&BsH[n * 64 + s * 8];
                bL[ns] = *(const short8*)&BsL[n * 64 + s * 8];
            }
            #pragma unroll
            for (int ms = 0; ms < 2; ++ms)
                #pragma unroll
                for (int ns = 0; ns < 4; ++ns) {
                    acc[ms][ns] = __builtin_amdgcn_mfma_f32_16x16x32_bf16(aH[ms], bH[ns], acc[ms][ns], 0, 0, 0);
                    acc[ms][ns] = __builtin_amdgcn_mfma_f32_16x16x32_bf16(aL[ms], bH[ns], acc[ms][ns], 0, 0, 0);
                    acc[ms][ns] = __builtin_amdgcn_mfma_f32_16x16x32_bf16(aH[ms], bL[ns], acc[ms][ns], 0, 0, 0);
                }
        }
    }

    #pragma unroll
    for (int ms = 0; ms < 2; ++ms) {
        int rbase = rows0 + wave * 32 + ms * 16 + quad * 4;
        #pragma unroll
        for (int ns = 0; ns < 4; ++ns) {
            int col = cols0 + ns * 16 + l15;
            #pragma unroll
            for (int r = 0; r < 4; ++r)
                C[(size_t)(rbase + r) * 256 + col] = acc[ms][ns][r] * scale;
        }
    }
}

// ---------------------------------------------------------------------------
// Fused scores + masked softmax + attn@V.  512 blocks (b = blk&15 swizzle),
// 2 queries/block, 256 threads.
// Phase 1 lane layout: key = lane>>4 (4 keys/wave/iter), h-chunk = lane&15;
// each lane's q/w fragments (16 elems x 2q + w) are REGISTER-resident, one
// prefetched float4 k-load per lane per iter -> trans-unit bound.
// score = Wsum - 2*sum_h w*rcp(exp2(xs)+1), xs pre-scaled by 2/ln2.
// Masked keys skipped: exp(-1e6 - max) == 0 exactly in fp32.
// ---------------------------------------------------------------------------
__global__ __launch_bounds__(256, 2) void attn_kernel(
    const float* __restrict__ qp,      // [B*NQ, H]  (pre-scaled; lives in d_out)
    const float* __restrict__ kp,      // [B*NK, H]  (pre-scaled; lives in d_ws)
    const float* __restrict__ values,  // [B, NK, VD]
    const int*   __restrict__ vlens,   // [B]
    const float* __restrict__ w_v,     // [H]
    float* __restrict__ out)           // [B, NQ, VD] (same rows as qp)
{
    __shared__ float q_s[2][HD];
    __shared__ float wv_s[HD];
    __shared__ float sc[2][NK];
    __shared__ float part[4][2][HD];
    __shared__ float redm[4], reds[4], invs[2];

    const int b     = blockIdx.x & 15;
    const int qpair = blockIdx.x >> 4;
    const int qi0   = qpair * 2;
    const int t     = threadIdx.x;
    const int lane  = t & 63;
    const int wave  = t >> 6;
    const int vl    = vlens[b];
    const size_t row0 = (size_t)b * NQ + qi0;

    q_s[0][t] = qp[row0 * HD + t];
    q_s[1][t] = qp[(row0 + 1) * HD + t];
    wv_s[t]   = w_v[t];
    __syncthreads();

    // Wsum = sum_h w_v[h]
    float Wsum;
    {
        float ws = wv_s[lane] + wv_s[lane + 64] + wv_s[lane + 128] + wv_s[lane + 192];
        #pragma unroll
        for (int off = 32; off; off >>= 1) ws += __shfl_xor(ws, off);
        Wsum = ws;
    }

    // register-resident q/w fragments: elements ch*4 + m*64 + {0..3}
    const int keyLoc = lane >> 4;     // 0..3
    const int ch     = lane & 15;     // 16B chunk id
    float4 qa[4], qb[4], wf[4];
    #pragma unroll
    for (int m = 0; m < 4; ++m) {
        qa[m] = *(const float4*)&q_s[0][ch * 4 + m * 64];
        qb[m] = *(const float4*)&q_s[1][ch * 4 + m * 64];
        wf[m] = *(const float4*)&wv_s[ch * 4 + m * 64];
    }

    // ---- phase 1: scores ----
    const float* kbase = kp + (size_t)b * NK * HD;
    const int n0 = wave * 4 + keyLoc;
    const float* kptr = kbase + (size_t)n0 * HD + ch * 4;

    float4 kk[4];
    if (n0 < vl) {
        #pragma unroll
        for (int m = 0; m < 4; ++m) kk[m] = *(const float4*)(kptr + m * 64);
    }

    for (int nBase = wave * 4; nBase < vl; nBase += 16) {
        const int nn = nBase + keyLoc;
        float4 kn[4];
        if (nn + 16 < vl) {
            #pragma unroll
            for (int m = 0; m < 4; ++m) kn[m] = *(const float4*)(kptr + 16 * HD + m * 64);
        }
        float p0 = 0.f, p1 = 0.f;
        if (nn < vl) {
            #pragma unroll
            for (int m = 0; m < 4; ++m) {
                float kv[4] = {kk[m].x, kk[m].y, kk[m].z, kk[m].w};
                float qav[4] = {qa[m].x, qa[m].y, qa[m].z, qa[m].w};
                float qbv[4] = {qb[m].x, qb[m].y, qb[m].z, qb[m].w};
                float wv4[4] = {wf[m].x, wf[m].y, wf[m].z, wf[m].w};
                #pragma unroll
                for (int c = 0; c < 4; ++c) {
                    float r0 = __builtin_amdgcn_rcpf(__builtin_amdgcn_exp2f(qav[c] + kv[c]) + 1.f);
                    float r1 = __builtin_amdgcn_rcpf(__builtin_amdgcn_exp2f(qbv[c] + kv[c]) + 1.f);
                    p0 = fmaf(wv4[c], r0, p0);
                    p1 = fmaf(wv4[c], r1, p1);
                }
            }
        }
        // reduce over 16 ch-lanes (same key)
        p0 += __shfl_down(p0, 8); p0 += __shfl_down(p0, 4);
        p0 += __shfl_down(p0, 2); p0 += __shfl_down(p0, 1);
        p1 += __shfl_down(p1, 8); p1 += __shfl_down(p1, 4);
        p1 += __shfl_down(p1, 2); p1 += __shfl_down(p1, 1);
        if (ch == 0 && nn < vl) {
            sc[0][nn] = fmaf(-2.f, p0, Wsum);
            sc[1][nn] = fmaf(-2.f, p1, Wsum);
        }
        #pragma unroll
        for (int m = 0; m < 4; ++m) kk[m] = kn[m];
        kptr += 16 * HD;
    }
    __syncthreads();

    // ---- phase 2: masked softmax, waves {0,1}->q0, {2,3}->q1 ----
    const int vla = (vl + 15) & ~15;
    {
        const int qq  = wave >> 1;
        const int sub = wave & 1;
        float m = -1e30f;
        for (int n = sub * 64 + lane; n < vl; n += 128) m = fmaxf(m, sc[qq][n]);
        #pragma unroll
        for (int off = 32; off; off >>= 1) m = fmaxf(m, __shfl_xor(m, off));
        if (lane == 0) redm[wave] = m;
        __syncthreads();
        m = fmaxf(redm[qq * 2], redm[qq * 2 + 1]);

        float ssum = 0.f;
        const float L2E = 1.4426950408889634f;
        for (int n = sub * 64 + lane; n < vl; n += 128) {
            float p = __builtin_amdgcn_exp2f((sc[qq][n] - m) * L2E);
            sc[qq][n] = p;
            ssum += p;
        }
        #pragma unroll
        for (int off = 32; off; off >>= 1) ssum += __shfl_xor(ssum, off);
        if (lane == 0) reds[wave] = ssum;
        if (vl + t < vla) { sc[0][vl + t] = 0.f; sc[1][vl + t] = 0.f; }
        __syncthreads();
        if (t == 0)  invs[0] = __builtin_amdgcn_rcpf(reds[0] + reds[1]);
        if (t == 64) invs[1] = __builtin_amdgcn_rcpf(reds[2] + reds[3]);
    }
    __syncthreads();

    // ---- phase 3: both outputs; batched V loads, guard-free ----
    float4 acc0 = {0.f, 0.f, 0.f, 0.f};
    float4 acc1 = {0.f, 0.f, 0.f, 0.f};
    const float* vbase = values + (size_t)b * NK * HD;
    for (int nb = wave * 4; nb < vla; nb += 16) {
        float4 v[4]; float pa[4], pb[4];
        #pragma unroll
        for (int u = 0; u < 4; ++u) {
            v[u]  = *(const float4*)&vbase[(size_t)(nb + u) * HD + lane * 4];
            pa[u] = sc[0][nb + u];
            pb[u] = sc[1][nb + u];
        }
        #pragma unroll
        for (int u = 0; u < 4; ++u) {
            acc0.x = fmaf(pa[u], v[u].x, acc0.x);
            acc0.y = fmaf(pa[u], v[u].y, acc0.y);
            acc0.z = fmaf(pa[u], v[u].z, acc0.z);
            acc0.w = fmaf(pa[u], v[u].w, acc0.w);
            acc1.x = fmaf(pb[u], v[u].x, acc1.x);
            acc1.y = fmaf(pb[u], v[u].y, acc1.y);
            acc1.z = fmaf(pb[u], v[u].z, acc1.z);
            acc1.w = fmaf(pb[u], v[u].w, acc1.w);
        }
    }
    *(float4*)&part[wave][0][lane * 4] = acc0;
    *(float4*)&part[wave][1][lane * 4] = acc1;
    __syncthreads();

    if (wave < 2) {
        float4 p0 = *(const float4*)&part[0][wave][lane * 4];
        float4 p1 = *(const float4*)&part[1][wave][lane * 4];
        float4 p2 = *(const float4*)&part[2][wave][lane * 4];
        float4 p3 = *(const float4*)&part[3][wave][lane * 4];
        const float inv = invs[wave];
        float4 o;
        o.x = ((p0.x + p1.x) + (p2.x + p3.x)) * inv;
        o.y = ((p0.y + p1.y) + (p2.y + p3.y)) * inv;
        o.z = ((p0.z + p1.z) + (p2.z + p3.z)) * inv;
        o.w = ((p0.w + p1.w) + (p2.w + p3.w)) * inv;
        *(float4*)&out[(row0 + wave) * HD + lane * 4] = o;
    }
}

extern "C" void kernel_launch(void* const* d_in, const int* in_sizes, int n_in,
                              void* d_out, int out_size, void* d_ws, size_t ws_size,
                              hipStream_t stream) {
    const float* queries = (const float*)d_in[0];  // [16,64,256]
    const float* keys    = (const float*)d_in[1];  // [16,512,256]
    const float* values  = (const float*)d_in[2];  // [16,512,256]
    const int*   vlens   = (const int*)d_in[3];    // [16]
    const float* W_q     = (const float*)d_in[4];  // [256,256]
    const float* W_k     = (const float*)d_in[5];  // [256,256]
    const float* w_v     = (const float*)d_in[6];  // [256]
    float* out = (float*)d_out;                    // [16,64,256] fp32

    // ws layout (ws_size = 256 MiB, we use 17.5 MB):
    float*  kp  = (float*)d_ws;                         // 8 MB
    ushort* qh  = (ushort*)((char*)d_ws + (8 << 20));   // 512 KB
    ushort* ql  = qh  + 1024 * 256;                     // 512 KB
    ushort* kh  = ql  + 1024 * 256;                     // 4 MB
    ushort* kl  = kh  + 8192 * 256;                     // 4 MB
    ushort* wqh = kl  + 8192 * 256;                     // 128 KB
    ushort* wql = wqh + 65536;
    ushort* wkh = wql + 65536;
    ushort* wkl = wkh + 65536;

    float* qp = out;   // qp lives in d_out; attn blocks overwrite only own rows

    const float SC = 2.885390081777927f;                // 2/ln(2)

    convert_split<<<dim3(2432), 256, 0, stream>>>(queries, keys, W_q, W_k,
                                                  qh, ql, kh, kl,
                                                  wqh, wql, wkh, wkl);
    proj_mfma2<<<dim3(72, 4), 256, 0, stream>>>(qh, ql, kh, kl,
                                                wqh, wql, wkh, wkl,
                                                qp, kp, SC);
    attn_kernel<<<dim3(512), 256, 0, stream>>>(qp, kp, values, vlens, w_v, out);
}

// Round 6
// 119.574 us; speedup vs baseline: 1.0332x; 1.0332x over previous
//
#include <hip/hip_runtime.h>
#include <hip/hip_bf16.h>

#define BB 16
#define NQ 64
#define NK 512
#define HD 256   // H = QS = KS = VD = 256

typedef __attribute__((ext_vector_type(8))) short short8;
typedef __attribute__((ext_vector_type(4))) float f32x4;

// fp32 -> bf16 round-to-nearest-even, bit-level
__device__ __forceinline__ ushort bf16_rne(float v) {
    unsigned u = __float_as_uint(v);
    return (ushort)((u + 0x7FFFu + ((u >> 16) & 1u)) >> 16);
}
__device__ __forceinline__ float bf16_to_f(ushort h) {
    return __uint_as_float(((unsigned)h) << 16);
}

// ---------------------------------------------------------------------------
// One-shot conversion (memory-bound, ~20 MB traffic):
//   queries/keys fp32 -> hi/lo bf16 arrays (same [row][k] layout)
//   W_q/W_k fp32 [k][n] -> hi/lo bf16 TRANSPOSED [n][k].
// W-part: per wave, n fixed, k4 spans the row -> scattered dword READS
// (L2-resident, cheap) + fully coalesced ushort4 row writes.
// ---------------------------------------------------------------------------
__global__ __launch_bounds__(256) void convert_split(
    const float* __restrict__ q, const float* __restrict__ k,
    const float* __restrict__ wq, const float* __restrict__ wk,
    ushort* __restrict__ qh, ushort* __restrict__ ql,
    ushort* __restrict__ kh, ushort* __restrict__ kl,
    ushort* __restrict__ wqh, ushort* __restrict__ wql,
    ushort* __restrict__ wkh, ushort* __restrict__ wkl)
{
    const int idx = blockIdx.x * 256 + threadIdx.x;
    if (blockIdx.x < 2304) {                     // A-part: (1024+8192)*256 elems
        int e = idx * 4;
        const float* src; ushort *dh, *dl; int off;
        if (e < 1024 * 256) { src = q; dh = qh; dl = ql; off = e; }
        else { src = k; dh = kh; dl = kl; off = e - 1024 * 256; }
        float4 v = *(const float4*)&src[off];
        float fv[4] = {v.x, v.y, v.z, v.w};
        ushort hh[4], ll[4];
        #pragma unroll
        for (int c = 0; c < 4; ++c) {
            hh[c] = bf16_rne(fv[c]);
            ll[c] = bf16_rne(fv[c] - bf16_to_f(hh[c]));
        }
        *(ushort4*)&dh[off] = make_ushort4(hh[0], hh[1], hh[2], hh[3]);
        *(ushort4*)&dl[off] = make_ushort4(ll[0], ll[1], ll[2], ll[3]);
    } else {                                     // W-part: 2 x 256x256 transpose
        int widx = idx - 2304 * 256;             // 0..32767
        const float* W; ushort *wh, *wl;
        if (widx < 16384) { W = wq; wh = wqh; wl = wql; }
        else { W = wk; wh = wkh; wl = wkl; widx -= 16384; }
        int n  = widx >> 6;                      // 0..255 (wave-uniform)
        int k4 = (widx & 63) * 4;                // 0..252 by 4
        ushort hh[4], ll[4];
        #pragma unroll
        for (int c = 0; c < 4; ++c) {
            float v = W[(k4 + c) * 256 + n];     // scattered read (L2)
            hh[c] = bf16_rne(v);
            ll[c] = bf16_rne(v - bf16_to_f(hh[c]));
        }
        *(ushort4*)&wh[n * 256 + k4] = make_ushort4(hh[0], hh[1], hh[2], hh[3]);
        *(ushort4*)&wl[n * 256 + k4] = make_ushort4(ll[0], ll[1], ll[2], ll[3]);
    }
}

// ---------------------------------------------------------------------------
// Lean split-bf16 MFMA GEMM:  C = A @ W  (AhWh + AlWh + AhWl), * scale.
// Block tile 128x64, BK=64, 4 waves (each 32x64).  XOR-swizzled LDS.
// Product-major MFMA order: dependency distance 8 between same-acc MFMAs.
// Global->reg prefetch of the next K-tile issued before the compute block.
// ---------------------------------------------------------------------------
__global__ __launch_bounds__(256, 2) void proj_mfma2(
    const ushort* __restrict__ qh, const ushort* __restrict__ ql,
    const ushort* __restrict__ kh, const ushort* __restrict__ kl,
    const ushort* __restrict__ wqh, const ushort* __restrict__ wql,
    const ushort* __restrict__ wkh, const ushort* __restrict__ wkl,
    float* __restrict__ qp, float* __restrict__ kp, float scale)
{
    __shared__ ushort AsH[128 * 64], AsL[128 * 64];
    __shared__ ushort BsH[64 * 64],  BsL[64 * 64];

    const ushort *Ah, *Al, *Bh, *Bl; float* C; int rows0;
    if (blockIdx.x < 8) { Ah = qh; Al = ql; Bh = wqh; Bl = wql; C = qp; rows0 = blockIdx.x * 128; }
    else                { Ah = kh; Al = kl; Bh = wkh; Bl = wkl; C = kp; rows0 = (blockIdx.x - 8) * 128; }
    const int cols0 = blockIdx.y * 64;

    const int t = threadIdx.x, lane = t & 63, wave = t >> 6;
    const int quad = lane >> 4, l15 = lane & 15;
    const int lr = lane >> 3;        // row-within-8 for staging
    const int cg = (lane & 7) ^ lr;  // swizzled chunk to fetch (per-lane const)
    const int swz0 = quad ^ (l15 & 7);
    const int swz1 = (quad + 4) ^ (l15 & 7);

    f32x4 acc[2][4];
    #pragma unroll
    for (int i = 0; i < 2; ++i)
        #pragma unroll
        for (int j = 0; j < 4; ++j)
            acc[i][j] = (f32x4){0.f, 0.f, 0.f, 0.f};

    short8 rAh[4], rAl[4], rBh[2], rBl[2];
    // preload K-tile 0
    #pragma unroll
    for (int i = 0; i < 4; ++i) {
        size_t g = (size_t)(rows0 + (wave * 4 + i) * 8 + lr) * 256 + cg * 8;
        rAh[i] = *(const short8*)&Ah[g];
        rAl[i] = *(const short8*)&Al[g];
    }
    #pragma unroll
    for (int j = 0; j < 2; ++j) {
        size_t g = (size_t)(cols0 + (wave * 2 + j) * 8 + lr) * 256 + cg * 8;
        rBh[j] = *(const short8*)&Bh[g];
        rBl[j] = *(const short8*)&Bl[g];
    }

    for (int k0 = 0; k0 < 256; k0 += 64) {
        __syncthreads();   // previous compute done before LDS overwrite
        #pragma unroll
        for (int i = 0; i < 4; ++i) {
            int ci = (wave * 4 + i) * 64 + lane;
            *(short8*)&AsH[ci * 8] = rAh[i];
            *(short8*)&AsL[ci * 8] = rAl[i];
        }
        #pragma unroll
        for (int j = 0; j < 2; ++j) {
            int ci = (wave * 2 + j) * 64 + lane;
            *(short8*)&BsH[ci * 8] = rBh[j];
            *(short8*)&BsL[ci * 8] = rBl[j];
        }
        __syncthreads();

        // prefetch next K-tile (overlaps the MFMA block below)
        if (k0 + 64 < 256) {
            #pragma unroll
            for (int i = 0; i < 4; ++i) {
                size_t g = (size_t)(rows0 + (wave * 4 + i) * 8 + lr) * 256 + k0 + 64 + cg * 8;
                rAh[i] = *(const short8*)&Ah[g];
                rAl[i] = *(const short8*)&Al[g];
            }
            #pragma unroll
            for (int j = 0; j < 2; ++j) {
                size_t g = (size_t)(cols0 + (wave * 2 + j) * 8 + lr) * 256 + k0 + 64 + cg * 8;
                rBh[j] = *(const short8*)&Bh[g];
                rBl[j] = *(const short8*)&Bl[g];
            }
        }

        #pragma unroll
        for (int ks = 0; ks < 2; ++ks) {
            const int s = ks ? swz1 : swz0;
            short8 aH[2], aL[2], bH[4], bL[4];
            #pragma unroll
            for (int ms = 0; ms < 2; ++ms) {
                int r = wave * 32 + ms * 16 + l15;
                aH[ms] = *(const short8*)&AsH[r * 64 + s * 8];
                aL[ms] = *(const short8*)&AsL[r * 64 + s * 8];
            }
            #pragma unroll
            for (int ns = 0; ns < 4; ++ns) {
                int n = ns * 16 + l15;
                bH[ns] = *(const short8*)&BsH[n * 64 + s * 8];
                bL[ns] = *(const short8*)&BsL[n * 64 + s * 8];
            }
            // product-major: same-acc MFMAs are 8 apart (no dep stall)
            #pragma unroll
            for (int ms = 0; ms < 2; ++ms)
                #pragma unroll
                for (int ns = 0; ns < 4; ++ns)
                    acc[ms][ns] = __builtin_amdgcn_mfma_f32_16x16x32_bf16(aH[ms], bH[ns], acc[ms][ns], 0, 0, 0);
            #pragma unroll
            for (int ms = 0; ms < 2; ++ms)
                #pragma unroll
                for (int ns = 0; ns < 4; ++ns)
                    acc[ms][ns] = __builtin_amdgcn_mfma_f32_16x16x32_bf16(aL[ms], bH[ns], acc[ms][ns], 0, 0, 0);
            #pragma unroll
            for (int ms = 0; ms < 2; ++ms)
                #pragma unroll
                for (int ns = 0; ns < 4; ++ns)
                    acc[ms][ns] = __builtin_amdgcn_mfma_f32_16x16x32_bf16(aH[ms], bL[ns], acc[ms][ns], 0, 0, 0);
        }
    }

    #pragma unroll
    for (int ms = 0; ms < 2; ++ms) {
        int rbase = rows0 + wave * 32 + ms * 16 + quad * 4;
        #pragma unroll
        for (int ns = 0; ns < 4; ++ns) {
            int col = cols0 + ns * 16 + l15;
            #pragma unroll
            for (int r = 0; r < 4; ++r)
                C[(size_t)(rbase + r) * 256 + col] = acc[ms][ns][r] * scale;
        }
    }
}

// ---------------------------------------------------------------------------
// Fused scores + masked softmax + attn@V.  512 blocks (b = blk&15 swizzle),
// 2 queries/block, 256 threads.  Phase 1 is GUARD-FREE: loops to vla
// (16-aligned), unconditional 1-ahead prefetch (overreads <=3 rows past the
// batch — lands in valid ws scratch; garbage scores at [vl,vla) are
// overwritten with 0 by phase 2 and never read by the softmax scans).
// score = Wsum - 2*sum_h w*rcp(exp2(xs)+1), xs pre-scaled by 2/ln2.
// Masked keys skipped: exp(-1e6 - max) == 0 exactly in fp32.
// ---------------------------------------------------------------------------
__global__ __launch_bounds__(256, 2) void attn_kernel(
    const float* __restrict__ qp,      // [B*NQ, H]  (pre-scaled; lives in d_out)
    const float* __restrict__ kp,      // [B*NK, H]  (pre-scaled; lives in d_ws)
    const float* __restrict__ values,  // [B, NK, VD]
    const int*   __restrict__ vlens,   // [B]
    const float* __restrict__ w_v,     // [H]
    float* __restrict__ out)           // [B, NQ, VD] (same rows as qp)
{
    __shared__ float q_s[2][HD];
    __shared__ float wv_s[HD];
    __shared__ float sc[2][NK];
    __shared__ float part[4][2][HD];
    __shared__ float redm[4], reds[4], invs[2];

    const int b     = blockIdx.x & 15;
    const int qpair = blockIdx.x >> 4;
    const int qi0   = qpair * 2;
    const int t     = threadIdx.x;
    const int lane  = t & 63;
    const int wave  = t >> 6;
    const int vl    = vlens[b];
    const int vla   = (vl + 15) & ~15;
    const size_t row0 = (size_t)b * NQ + qi0;

    q_s[0][t] = qp[row0 * HD + t];
    q_s[1][t] = qp[(row0 + 1) * HD + t];
    wv_s[t]   = w_v[t];
    __syncthreads();

    // Wsum = sum_h w_v[h]
    float Wsum;
    {
        float ws = wv_s[lane] + wv_s[lane + 64] + wv_s[lane + 128] + wv_s[lane + 192];
        #pragma unroll
        for (int off = 32; off; off >>= 1) ws += __shfl_xor(ws, off);
        Wsum = ws;
    }

    // register-resident q/w fragments: elements ch*4 + m*64 + {0..3}
    const int keyLoc = lane >> 4;     // 0..3
    const int ch     = lane & 15;     // 16B chunk id
    float4 qa[4], qb[4], wf[4];
    #pragma unroll
    for (int m = 0; m < 4; ++m) {
        qa[m] = *(const float4*)&q_s[0][ch * 4 + m * 64];
        qb[m] = *(const float4*)&q_s[1][ch * 4 + m * 64];
        wf[m] = *(const float4*)&wv_s[ch * 4 + m * 64];
    }

    // ---- phase 1: scores (guard-free, pipelined) ----
    const float* kbase = kp + (size_t)b * NK * HD;
    const float* kptr  = kbase + (size_t)(wave * 4 + keyLoc) * HD + ch * 4;

    float4 kk[4];
    #pragma unroll
    for (int m = 0; m < 4; ++m) kk[m] = *(const float4*)(kptr + m * 64);

    for (int nb = wave * 4; nb < vla; nb += 16) {
        float4 kn[4];
        #pragma unroll
        for (int m = 0; m < 4; ++m) kn[m] = *(const float4*)(kptr + 16 * HD + m * 64);

        float p0 = 0.f, p1 = 0.f;
        #pragma unroll
        for (int m = 0; m < 4; ++m) {
            float kv[4]  = {kk[m].x, kk[m].y, kk[m].z, kk[m].w};
            float qav[4] = {qa[m].x, qa[m].y, qa[m].z, qa[m].w};
            float qbv[4] = {qb[m].x, qb[m].y, qb[m].z, qb[m].w};
            float wv4[4] = {wf[m].x, wf[m].y, wf[m].z, wf[m].w};
            #pragma unroll
            for (int c = 0; c < 4; ++c) {
                float r0 = __builtin_amdgcn_rcpf(__builtin_amdgcn_exp2f(qav[c] + kv[c]) + 1.f);
                float r1 = __builtin_amdgcn_rcpf(__builtin_amdgcn_exp2f(qbv[c] + kv[c]) + 1.f);
                p0 = fmaf(wv4[c], r0, p0);
                p1 = fmaf(wv4[c], r1, p1);
            }
        }
        // reduce over 16 ch-lanes (same key)
        p0 += __shfl_down(p0, 8); p0 += __shfl_down(p0, 4);
        p0 += __shfl_down(p0, 2); p0 += __shfl_down(p0, 1);
        p1 += __shfl_down(p1, 8); p1 += __shfl_down(p1, 4);
        p1 += __shfl_down(p1, 2); p1 += __shfl_down(p1, 1);
        if (ch == 0) {
            sc[0][nb + keyLoc] = fmaf(-2.f, p0, Wsum);
            sc[1][nb + keyLoc] = fmaf(-2.f, p1, Wsum);
        }
        #pragma unroll
        for (int m = 0; m < 4; ++m) kk[m] = kn[m];
        kptr += 16 * HD;
    }
    __syncthreads();

    // ---- phase 2: masked softmax, waves {0,1}->q0, {2,3}->q1 ----
    {
        const int qq  = wave >> 1;
        const int sub = wave & 1;
        float m = -1e30f;
        for (int n = sub * 64 + lane; n < vl; n += 128) m = fmaxf(m, sc[qq][n]);
        #pragma unroll
        for (int off = 32; off; off >>= 1) m = fmaxf(m, __shfl_xor(m, off));
        if (lane == 0) redm[wave] = m;
        __syncthreads();
        m = fmaxf(redm[qq * 2], redm[qq * 2 + 1]);

        float ssum = 0.f;
        const float L2E = 1.4426950408889634f;
        for (int n = sub * 64 + lane; n < vl; n += 128) {
            float p = __builtin_amdgcn_exp2f((sc[qq][n] - m) * L2E);
            sc[qq][n] = p;
            ssum += p;
        }
        #pragma unroll
        for (int off = 32; off; off >>= 1) ssum += __shfl_xor(ssum, off);
        if (lane == 0) reds[wave] = ssum;
        if (vl + t < vla) { sc[0][vl + t] = 0.f; sc[1][vl + t] = 0.f; }
        __syncthreads();
        if (t == 0)  invs[0] = __builtin_amdgcn_rcpf(reds[0] + reds[1]);
        if (t == 64) invs[1] = __builtin_amdgcn_rcpf(reds[2] + reds[3]);
    }
    __syncthreads();

    // ---- phase 3: both outputs; batched V loads, guard-free ----
    float4 acc0 = {0.f, 0.f, 0.f, 0.f};
    float4 acc1 = {0.f, 0.f, 0.f, 0.f};
    const float* vbase = values + (size_t)b * NK * HD;
    for (int nb = wave * 4; nb < vla; nb += 16) {
        float4 v[4]; float pa[4], pb[4];
        #pragma unroll
        for (int u = 0; u < 4; ++u) {
            v[u]  = *(const float4*)&vbase[(size_t)(nb + u) * HD + lane * 4];
            pa[u] = sc[0][nb + u];
            pb[u] = sc[1][nb + u];
        }
        #pragma unroll
        for (int u = 0; u < 4; ++u) {
            acc0.x = fmaf(pa[u], v[u].x, acc0.x);
            acc0.y = fmaf(pa[u], v[u].y, acc0.y);
            acc0.z = fmaf(pa[u], v[u].z, acc0.z);
            acc0.w = fmaf(pa[u], v[u].w, acc0.w);
            acc1.x = fmaf(pb[u], v[u].x, acc1.x);
            acc1.y = fmaf(pb[u], v[u].y, acc1.y);
            acc1.z = fmaf(pb[u], v[u].z, acc1.z);
            acc1.w = fmaf(pb[u], v[u].w, acc1.w);
        }
    }
    *(float4*)&part[wave][0][lane * 4] = acc0;
    *(float4*)&part[wave][1][lane * 4] = acc1;
    __syncthreads();

    if (wave < 2) {
        float4 p0 = *(const float4*)&part[0][wave][lane * 4];
        float4 p1 = *(const float4*)&part[1][wave][lane * 4];
        float4 p2 = *(const float4*)&part[2][wave][lane * 4];
        float4 p3 = *(const float4*)&part[3][wave][lane * 4];
        const float inv = invs[wave];
        float4 o;
        o.x = ((p0.x + p1.x) + (p2.x + p3.x)) * inv;
        o.y = ((p0.y + p1.y) + (p2.y + p3.y)) * inv;
        o.z = ((p0.z + p1.z) + (p2.z + p3.z)) * inv;
        o.w = ((p0.w + p1.w) + (p2.w + p3.w)) * inv;
        *(float4*)&out[(row0 + wave) * HD + lane * 4] = o;
    }
}

extern "C" void kernel_launch(void* const* d_in, const int* in_sizes, int n_in,
                              void* d_out, int out_size, void* d_ws, size_t ws_size,
                              hipStream_t stream) {
    const float* queries = (const float*)d_in[0];  // [16,64,256]
    const float* keys    = (const float*)d_in[1];  // [16,512,256]
    const float* values  = (const float*)d_in[2];  // [16,512,256]
    const int*   vlens   = (const int*)d_in[3];    // [16]
    const float* W_q     = (const float*)d_in[4];  // [256,256]
    const float* W_k     = (const float*)d_in[5];  // [256,256]
    const float* w_v     = (const float*)d_in[6];  // [256]
    float* out = (float*)d_out;                    // [16,64,256] fp32

    // ws layout (uses ~17.5 MB of the 256 MiB ws):
    float*  kp  = (float*)d_ws;                         // 8 MB
    ushort* qh  = (ushort*)((char*)d_ws + (8 << 20));   // 512 KB
    ushort* ql  = qh  + 1024 * 256;                     // 512 KB
    ushort* kh  = ql  + 1024 * 256;                     // 4 MB
    ushort* kl  = kh  + 8192 * 256;                     // 4 MB
    ushort* wqh = kl  + 8192 * 256;                     // 128 KB
    ushort* wql = wqh + 65536;
    ushort* wkh = wql + 65536;
    ushort* wkl = wkh + 65536;

    float* qp = out;   // qp lives in d_out; attn blocks overwrite only own rows

    const float SC = 2.885390081777927f;                // 2/ln(2)

    convert_split<<<dim3(2432), 256, 0, stream>>>(queries, keys, W_q, W_k,
                                                  qh, ql, kh, kl,
                                                  wqh, wql, wkh, wkl);
    proj_mfma2<<<dim3(72, 4), 256, 0, stream>>>(qh, ql, kh, kl,
                                                wqh, wql, wkh, wkl,
                                                qp, kp, SC);
    attn_kernel<<<dim3(512), 256, 0, stream>>>(qp, kp, values, vlens, w_v, out);
}